// Round 5
// baseline (1738.123 us; speedup 1.0000x reference)
//
#include <hip/hip_runtime.h>
#include <math.h>

#define NTOK 32768
#define DDIM 768
#define HDIM 3072
#define NEXP 8
#define CAP  10240

typedef short short8 __attribute__((ext_vector_type(8)));
typedef float f32x4 __attribute__((ext_vector_type(4)));

__device__ __forceinline__ unsigned short f2bf(float f) {
  unsigned u = __float_as_uint(f);
  u += 0x7FFFu + ((u >> 16) & 1u);   // round-to-nearest-even (finite inputs)
  return (unsigned short)(u >> 16);
}
__device__ __forceinline__ float bf2f(unsigned short h) {
  return __uint_as_float((unsigned)h << 16);
}

__device__ __forceinline__ void gload16(const void* g, void* l) {
  __builtin_amdgcn_global_load_lds(
      (const __attribute__((address_space(1))) void*)g,
      (__attribute__((address_space(3))) void*)l, 16, 0, 0);
}

// Fast exact-GELU: 0.5*v*(1+erf(v/sqrt2)), erf via A&S 7.1.26 (|err|<1.5e-7).
__device__ __forceinline__ float gelu_fast(float v) {
  float z = v * 0.70710678118654752f;
  float a = fabsf(z);
  float t = 1.0f / (1.0f + 0.3275911f * a);
  float p = t * (0.254829592f +
           t * (-0.284496736f +
           t * (1.421413741f +
           t * (-1.453152027f +
           t * 1.061405429f))));
  float ex = __expf(-a * a);
  float er = 1.0f - p * ex;
  er = copysignf(er, z);
  return 0.5f * v * (1.0f + er);
}

// ---------------------------------------------------------------------------
// Router: per-token top-2 + softmax + x->bf16 + SLOT ASSIGNMENT (fused).
// Per block (32 tokens): LDS counts -> one atomicAdd per expert -> in-block
// ranks. Slot order across blocks is nondeterministic; safe because each
// token's output rows are computed independently of slot position, and
// capacity is never exceeded (E[cnt]=8192, sigma~78, CAP=10240).
// cnt[] must be zeroed before launch (hipMemsetAsync).
// ---------------------------------------------------------------------------
__global__ __launch_bounds__(256) void router_assign(
    const float* __restrict__ x, const float* __restrict__ wg,
    unsigned short* __restrict__ xb,
    float* __restrict__ pw, int* __restrict__ cnt,
    int* __restrict__ tokidx, int* __restrict__ slotof)
{
  __shared__ float wt[NEXP][DDIM];       // transposed gate, 24 KB
  __shared__ unsigned spair[32];
  __shared__ int sbase[NEXP];
  int t = threadIdx.x;
  for (int idx = t; idx < NEXP * DDIM; idx += 256) {
    int d = idx >> 3, e = idx & 7;       // wg is [768][8] row-major
    wt[e][d] = wg[idx];
  }
  __syncthreads();
  int wave = t >> 6, lane = t & 63;
  int n0 = blockIdx.x * 32 + wave * 8;
  for (int i = 0; i < 8; ++i) {
    int n = n0 + i;
    const float* xr = x + (size_t)n * DDIM;
    unsigned short* xbr = xb + (size_t)n * DDIM;
    float acc[NEXP];
#pragma unroll
    for (int e = 0; e < NEXP; ++e) acc[e] = 0.f;
#pragma unroll
    for (int c = 0; c < 3; ++c) {
      int d = c * 256 + lane * 4;
      float4 xv = *(const float4*)(xr + d);
      ushort4 pk;
      pk.x = f2bf(xv.x); pk.y = f2bf(xv.y); pk.z = f2bf(xv.z); pk.w = f2bf(xv.w);
      *(ushort4*)(xbr + d) = pk;
#pragma unroll
      for (int e = 0; e < NEXP; ++e) {
        float4 wv = *(const float4*)(&wt[e][d]);
        acc[e] += xv.x * wv.x + xv.y * wv.y + xv.z * wv.z + xv.w * wv.w;
      }
    }
#pragma unroll
    for (int e = 0; e < NEXP; ++e) {
      float v = acc[e];
      for (int o = 32; o > 0; o >>= 1) v += __shfl_xor(v, o, 64);
      acc[e] = v;
    }
    if (lane == 0) {
      int e1 = 0; float l1 = acc[0];
#pragma unroll
      for (int e = 1; e < NEXP; ++e) if (acc[e] > l1) { l1 = acc[e]; e1 = e; }
      int e2 = -1; float l2 = -INFINITY;
#pragma unroll
      for (int e = 0; e < NEXP; ++e) if (e != e1 && acc[e] > l2) { l2 = acc[e]; e2 = e; }
      float p1 = 1.f / (1.f + expf(l2 - l1));   // stable 2-way softmax
      spair[wave * 8 + i] = (unsigned)e1 | ((unsigned)e2 << 8);
      pw[n] = p1;
    }
  }
  __syncthreads();
  int e1 = 0, e2 = 0, r1 = 0, r2 = 0;
  if (t < 32) {
    unsigned mep = spair[t];
    e1 = mep & 255; e2 = (mep >> 8) & 255;
    for (int j = 0; j < t; ++j) {
      unsigned pj = spair[j];
      int f1 = pj & 255, f2 = (pj >> 8) & 255;
      r1 += (f1 == e1) + (f2 == e1);
      r2 += (f1 == e2) + (f2 == e2);
    }
  }
  if (t < NEXP) {
    int tot = 0;
    for (int j = 0; j < 32; ++j) {
      unsigned pj = spair[j];
      tot += ((pj & 255) == (unsigned)t) + (((pj >> 8) & 255) == (unsigned)t);
    }
    sbase[t] = atomicAdd(&cnt[t], tot);
  }
  __syncthreads();
  if (t < 32) {
    int n = blockIdx.x * 32 + t;
    int g1 = sbase[e1] + r1;
    int g2 = sbase[e2] + r2;
    if (g1 < CAP) { tokidx[e1 * CAP + g1] = n; slotof[2 * n] = e1 * CAP + g1; }
    else slotof[2 * n] = -1;
    if (g2 < CAP) { tokidx[e2 * CAP + g2] = n; slotof[2 * n + 1] = e2 * CAP + g2; }
    else slotof[2 * n + 1] = -1;
  }
}

// ---------------------------------------------------------------------------
// Both weight transposes in ONE launch: src [E][R][C] -> dst [E][C][R] (bf16)
// ---------------------------------------------------------------------------
__global__ __launch_bounds__(256) void transpose_all(
    const float* __restrict__ w1, const float* __restrict__ w2,
    unsigned short* __restrict__ d1, unsigned short* __restrict__ d2)
{
  __shared__ float tile[64][65];
  int bid = blockIdx.x;
  int half = bid / (576 * NEXP);
  int r = bid - half * 576 * NEXP;
  int e = r / 576, rr = r - e * 576;
  const float* src; unsigned short* dst; int R, C, cx, cy;
  if (half == 0) { src = w1; dst = d1; R = DDIM; C = HDIM; cx = rr % 48; cy = rr / 48; }
  else           { src = w2; dst = d2; R = HDIM; C = DDIM; cx = rr % 12; cy = rr / 12; }
  const float* s = src + (size_t)e * R * C;
  unsigned short* d = dst + (size_t)e * R * C;
  int c0 = cx * 64, r0 = cy * 64;
  int tc = threadIdx.x & 63, tg = threadIdx.x >> 6;
#pragma unroll
  for (int q = tg; q < 64; q += 4)
    tile[q][tc] = s[(size_t)(r0 + q) * C + c0 + tc];
  __syncthreads();
#pragma unroll
  for (int q = tg; q < 64; q += 4)
    d[(size_t)(c0 + q) * R + r0 + tc] = f2bf(tile[tc][q]);
}

// ---------------------------------------------------------------------------
// PERSISTENT grouped GEMM, 256x256-tile 8-phase schedule with seamless
// cross-tile bridging. Each block owns a contiguous XCD-chunked range of
// logical tiles tau=(e,by,bx). Per tile: NI-1 steady iterations + a BRIDGE
// iteration whose ph2..ph7 stages target the NEXT tile's first 3 half-tile
// pairs (position-identical to the steady schedule -> all vmcnt/WAR
// invariants preserved), then the epilogue. Prologue paid once per block.
// Steady vmcnt(8) at every odd phase: each wait completes exactly the
// half-tile the next phase reads, staged 6 phases (~1000cy) earlier.
// Epilogue stores inflate vmcnt once per tile -> first post-tile wait
// over-drains (safe, self-heals by ph3).
// T2 swizzle: chunk ^= (row>>1)&3 (pre-swizzled global source, same XOR on
// ds_read) -> measured 0 bank conflicts.
// EPI=0: Obuf[e*Mc + row] = gelu(gather(xb) @ w1bt^T + b1)        (bf16)
// EPI=1: Obuf[e*CAP + gm] = Hbuf @ w2bt^T + b2  (bf16, un-weighted)
// ---------------------------------------------------------------------------
template<int EPI, int KK, int NN>
__global__ __launch_bounds__(512, 2) void moe_gemm(
    const unsigned short* __restrict__ A,
    const unsigned short* __restrict__ Bt,
    const float* __restrict__ bias,
    const int* __restrict__ cnt,
    const int* __restrict__ tokidx,
    unsigned short* __restrict__ Obuf,
    int mbase, int Mc, int mt)
{
  constexpr int KT = KK / 64;     // K-tiles of 64
  constexpr int NI = KT / 2;      // 2 K-tiles per iteration (NI >= 2)
  constexpr int GX = NN / 256;    // N-tiles

  int t = threadIdx.x, wave = t >> 6, lane = t & 63;
  int wr = wave >> 2, wc = wave & 3;    // 2M x 4N wave grid
  int lane15 = lane & 15, quad = lane >> 4;

  __shared__ __align__(16) char smem[131072];

  // staging geometry: each thread owns 2 of the 1024 16B-chunks per half-tile
  int ci0 = wave * 128 + lane;
  int ci1 = ci0 + 64;
  int r0 = ci0 >> 2, r1 = ci1 >> 2;     // tile row 0..255
  int c0 = (ci0 & 3) ^ ((r0 >> 1) & 3); // pre-swizzled source chunk in K-half
  int c1 = (ci1 & 3) ^ ((r1 >> 1) & 3);

  // ---- block's tile range (XCD-chunked, balanced) ----
  int L = NEXP * mt * GX;
  int per_e = mt * GX;
  int g = gridDim.x;                    // multiple of 8
  int p = (blockIdx.x & 7) * (g >> 3) + (blockIdx.x >> 3);
  int q = L / g, rr_ = L % g;
  int s_ = p * q + (p < rr_ ? p : rr_);
  int endi = s_ + q + (p < rr_ ? 1 : 0);

  const unsigned short *cA0, *cA1, *cB0, *cB1;
  int cE, cLy, cGm, cN0, cM;

  // tile decode + pointer build; returns false if tile inactive
  auto mktile = [&](int tau, const unsigned short*& A0, const unsigned short*& A1,
                    const unsigned short*& B0, const unsigned short*& B1,
                    int& tE, int& tLy, int& tGm, int& tN0, int& tM) -> bool {
    int e = tau / per_e; int rem = tau - e * per_e;
    int by = rem / GX; int bx = rem - by * GX;
    int M = cnt[e]; if (M > CAP) M = CAP;
    int ly0 = by * 256, gm0 = mbase + ly0, n0 = bx * 256;
    tE = e; tLy = ly0; tGm = gm0; tN0 = n0; tM = M;
    if (gm0 >= M) return false;
    if (EPI == 0) {
      int g0 = gm0 + r0; if (g0 >= M) g0 = M - 1;
      int g1 = gm0 + r1; if (g1 >= M) g1 = M - 1;
      A0 = A + (size_t)tokidx[e * CAP + g0] * KK + c0 * 8;
      A1 = A + (size_t)tokidx[e * CAP + g1] * KK + c1 * 8;
    } else {
      A0 = A + ((size_t)e * Mc + ly0 + r0) * KK + c0 * 8;
      A1 = A + ((size_t)e * Mc + ly0 + r1) * KK + c1 * 8;
    }
    B0 = Bt + ((size_t)e * NN + n0 + r0) * KK + c0 * 8;
    B1 = Bt + ((size_t)e * NN + n0 + r1) * KK + c1 * 8;
    return true;
  };

  int ci = s_;
  bool have = false;
  for (; ci < endi; ++ci)
    if (mktile(ci, cA0, cA1, cB0, cB1, cE, cLy, cGm, cN0, cM)) { have = true; break; }
  if (!have) return;

  // ---- ds_read fragment offsets (swizzled) ----
  int aoffb[8], boffb[4];
#pragma unroll
  for (int m = 0; m < 8; ++m) {
    int row = wr * 128 + m * 16 + lane15;
    aoffb[m] = row * 64 + ((quad ^ ((row >> 1) & 3)) * 16);
  }
#pragma unroll
  for (int n = 0; n < 4; ++n) {
    int row = wc * 64 + n * 16 + lane15;
    boffb[n] = 32768 + row * 64 + ((quad ^ ((row >> 1) & 3)) * 16);
  }

  short8 af[4], bf[4];

  // dst_off = buf*65536 + (B?32768:0) + kh*16384 ; src_off = kt*64 + kh*32
#define STG(P0, P1, dst_off, src_off) do { \
    gload16((P0) + (src_off), smem + (dst_off) + wave * 2048); \
    gload16((P1) + (src_off), smem + (dst_off) + wave * 2048 + 1024); \
  } while (0)
#define BAR()  __builtin_amdgcn_s_barrier()
#define WVM8() asm volatile("s_waitcnt vmcnt(8)" ::: "memory")
#define RD_B(buf, ks) do { \
    _Pragma("unroll") \
    for (int n = 0; n < 4; ++n) \
      bf[n] = *(const short8*)(smem + (buf) * 65536 + (ks) * 16384 + boffb[n]); \
  } while (0)
#define RD_A(buf, ks, mh) do { \
    _Pragma("unroll") \
    for (int m = 0; m < 4; ++m) \
      af[m] = *(const short8*)(smem + (buf) * 65536 + (ks) * 16384 + aoffb[(mh) * 4 + m]); \
  } while (0)
#define MM(mh) do { \
    __builtin_amdgcn_s_setprio(1); \
    _Pragma("unroll") \
    for (int m = 0; m < 4; ++m) \
      _Pragma("unroll") \
      for (int n = 0; n < 4; ++n) \
        acc[(mh) * 4 + m][n] = __builtin_amdgcn_mfma_f32_16x16x32_bf16( \
            af[m], bf[n], acc[(mh) * 4 + m][n], 0, 0, 0); \
    __builtin_amdgcn_s_setprio(0); \
  } while (0)

  // ---- prologue (once per block): buf0 <- tile0 (4 halves), buf1.kh0 <- tile1
  STG(cA0, cA1, 0,             0);   STG(cB0, cB1, 32768,         0);
  STG(cA0, cA1, 16384,        32);   STG(cB0, cB1, 49152,        32);
  STG(cA0, cA1, 65536,        64);   STG(cB0, cB1, 98304,        64);
  WVM8();
  BAR();

  for (;;) {
    // find next active tile (bridge target); dummy = cur if none
    int nj = ci + 1;
    const unsigned short *nA0 = cA0, *nA1 = cA1, *nB0 = cB0, *nB1 = cB1;
    int nE, nLy, nGm, nN0, nM;
    bool hn = false;
    for (; nj < endi; ++nj)
      if (mktile(nj, nA0, nA1, nB0, nB1, nE, nLy, nGm, nN0, nM)) { hn = true; break; }

    f32x4 acc[8][4];
#pragma unroll
    for (int mf = 0; mf < 8; ++mf)
#pragma unroll
      for (int n = 0; n < 4; ++n)
#pragma unroll
        for (int r2 = 0; r2 < 4; ++r2) acc[mf][n][r2] = 0.f;

#pragma unroll 1
    for (int it = 0; it < NI - 1; ++it) {
      int kt = 2 * it;
      // ph0
      RD_B(0, 0); RD_A(0, 0, 0); STG(cA0, cA1, 81920, (kt + 1) * 64 + 32);
      BAR(); MM(0); BAR();
      // ph1
      RD_A(0, 0, 1); STG(cB0, cB1, 114688, (kt + 1) * 64 + 32);
      BAR(); MM(1); WVM8(); BAR();
      // ph2
      RD_B(0, 1); RD_A(0, 1, 0); STG(cA0, cA1, 0, (kt + 2) * 64);
      BAR(); MM(0); BAR();
      // ph3
      RD_A(0, 1, 1); STG(cB0, cB1, 32768, (kt + 2) * 64);
      BAR(); MM(1); WVM8(); BAR();
      // ph4
      RD_B(1, 0); RD_A(1, 0, 0); STG(cA0, cA1, 16384, (kt + 2) * 64 + 32);
      BAR(); MM(0); BAR();
      // ph5
      RD_A(1, 0, 1); STG(cB0, cB1, 49152, (kt + 2) * 64 + 32);
      BAR(); MM(1); WVM8(); BAR();
      // ph6
      RD_B(1, 1); RD_A(1, 1, 0); STG(cA0, cA1, 65536, (kt + 3) * 64);
      BAR(); MM(0); BAR();
      // ph7
      RD_A(1, 1, 1); STG(cB0, cB1, 98304, (kt + 3) * 64);
      BAR(); MM(1); WVM8(); BAR();
    }

    // ---- BRIDGE iteration (kt = KT-2): ph0/ph1 finish cur tile1.kh1;
    //      ph2..ph7 stage NEXT tile's {t0.kh0, t0.kh1, t1.kh0}
    {
      constexpr int kt = KT - 2;
      RD_B(0, 0); RD_A(0, 0, 0); STG(cA0, cA1, 81920, (kt + 1) * 64 + 32);
      BAR(); MM(0); BAR();
      RD_A(0, 0, 1); STG(cB0, cB1, 114688, (kt + 1) * 64 + 32);
      BAR(); MM(1); WVM8(); BAR();
      RD_B(0, 1); RD_A(0, 1, 0); STG(nA0, nA1, 0, 0);
      BAR(); MM(0); BAR();
      RD_A(0, 1, 1); STG(nB0, nB1, 32768, 0);
      BAR(); MM(1); WVM8(); BAR();
      RD_B(1, 0); RD_A(1, 0, 0); STG(nA0, nA1, 16384, 32);
      BAR(); MM(0); BAR();
      RD_A(1, 0, 1); STG(nB0, nB1, 49152, 32);
      BAR(); MM(1); WVM8(); BAR();
      RD_B(1, 1); RD_A(1, 1, 0); STG(nA0, nA1, 65536, 64);
      BAR(); MM(0); BAR();
      RD_A(1, 1, 1); STG(nB0, nB1, 98304, 64);
      BAR(); MM(1); WVM8(); BAR();
    }

    // ---- epilogue for cur (no LDS reads -> safe vs in-flight stages) ----
    if (EPI == 0) {
#pragma unroll
      for (int n = 0; n < 4; ++n) {
        int col = cN0 + wc * 64 + n * 16 + lane15;
        float bcol = bias[cE * NN + col];
#pragma unroll
        for (int mf = 0; mf < 8; ++mf) {
          int rowb = cLy + wr * 128 + mf * 16 + quad * 4;
#pragma unroll
          for (int r2 = 0; r2 < 4; ++r2) {
            float v = gelu_fast(acc[mf][n][r2] + bcol);
            Obuf[((size_t)cE * Mc + rowb + r2) * NN + col] = f2bf(v);
          }
        }
      }
    } else {
      float bc[4];
#pragma unroll
      for (int n = 0; n < 4; ++n)
        bc[n] = bias[cE * NN + cN0 + wc * 64 + n * 16 + lane15];
#pragma unroll
      for (int mf = 0; mf < 8; ++mf) {
        int gmb = cGm + wr * 128 + mf * 16 + quad * 4;
#pragma unroll
        for (int r2 = 0; r2 < 4; ++r2) {
          int gm = gmb + r2;
          if (gm < cM) {
            unsigned short* yrow = Obuf + ((size_t)cE * CAP + gm) * NN;
#pragma unroll
            for (int n = 0; n < 4; ++n) {
              int col = cN0 + wc * 64 + n * 16 + lane15;
              yrow[col] = f2bf(acc[mf][n][r2] + bc[n]);
            }
          }
        }
      }
    }

    if (!hn) break;
    cA0 = nA0; cA1 = nA1; cB0 = nB0; cB1 = nB1;
    cE = nE; cLy = nLy; cGm = nGm; cN0 = nN0; cM = nM;
    ci = nj;
  }
#undef STG
#undef BAR
#undef WVM8
#undef RD_B
#undef RD_A
#undef MM
}

// ---------------------------------------------------------------------------
// Fused combine + LayerNorm, one wave per token, vectorized ushort4 loads.
// ---------------------------------------------------------------------------
__global__ __launch_bounds__(512) void combine_ln(
    const unsigned short* __restrict__ Y, const int* __restrict__ slotof,
    const float* __restrict__ pw,
    const float* __restrict__ lnw, const float* __restrict__ lnb,
    float* __restrict__ out)
{
  int w = threadIdx.x >> 6, lane = threadIdx.x & 63;
  int n = blockIdx.x * 8 + w;
  int s0 = slotof[2 * n], s1 = slotof[2 * n + 1];
  float p0 = pw[n], p1 = 1.f - p0;
  const unsigned short* y0 = Y + (size_t)(s0 < 0 ? 0 : s0) * DDIM;
  const unsigned short* y1 = Y + (size_t)(s1 < 0 ? 0 : s1) * DDIM;
  if (s0 < 0) p0 = 0.f;
  if (s1 < 0) p1 = 0.f;
  float v[12];
  float s = 0.f, ss = 0.f;
#pragma unroll
  for (int c = 0; c < 3; ++c) {
    int d = c * 256 + lane * 4;
    ushort4 a = *(const ushort4*)(y0 + d);
    ushort4 b = *(const ushort4*)(y1 + d);
    float4 fa = { bf2f(a.x), bf2f(a.y), bf2f(a.z), bf2f(a.w) };
    float4 fb = { bf2f(b.x), bf2f(b.y), bf2f(b.z), bf2f(b.w) };
    v[c * 4 + 0] = p0 * fa.x + p1 * fb.x;
    v[c * 4 + 1] = p0 * fa.y + p1 * fb.y;
    v[c * 4 + 2] = p0 * fa.z + p1 * fb.z;
    v[c * 4 + 3] = p0 * fa.w + p1 * fb.w;
#pragma unroll
    for (int j = 0; j < 4; ++j) { s += v[c * 4 + j]; ss += v[c * 4 + j] * v[c * 4 + j]; }
  }
  for (int o = 32; o > 0; o >>= 1) { s += __shfl_xor(s, o, 64); ss += __shfl_xor(ss, o, 64); }
  float mu = s * (1.f / DDIM);
  float var = ss * (1.f / DDIM) - mu * mu;
  float rs = rsqrtf(var + 1e-5f);
  float* row = out + (size_t)n * DDIM;
#pragma unroll
  for (int c = 0; c < 3; ++c) {
    int d = c * 256 + lane * 4;
    float4 lw = *(const float4*)(lnw + d);
    float4 lb = *(const float4*)(lnb + d);
    float4 o;
    o.x = (v[c * 4 + 0] - mu) * rs * lw.x + lb.x;
    o.y = (v[c * 4 + 1] - mu) * rs * lw.y + lb.y;
    o.z = (v[c * 4 + 2] - mu) * rs * lw.z + lb.z;
    o.w = (v[c * 4 + 3] - mu) * rs * lw.w + lb.w;
    *(float4*)(row + d) = o;
  }
}

// sentinel fill: signals "workspace too small" via a distinctive absmax
__global__ void sentinel_kernel(float* __restrict__ out, int n) {
  int i = blockIdx.x * 256 + threadIdx.x;
  if (i < n) out[i] = 12345.0f;
}

// ---------------------------------------------------------------------------
extern "C" void kernel_launch(void* const* d_in, const int* in_sizes, int n_in,
                              void* d_out, int out_size, void* d_ws, size_t ws_size,
                              hipStream_t stream)
{
  const float* x   = (const float*)d_in[0];
  const float* wg  = (const float*)d_in[1];
  const float* w1  = (const float*)d_in[2];
  const float* b1  = (const float*)d_in[3];
  const float* w2  = (const float*)d_in[4];
  const float* b2  = (const float*)d_in[5];
  const float* lnw = (const float*)d_in[6];
  const float* lnb = (const float*)d_in[7];
  float* out = (float*)d_out;

  char* ws = (char*)d_ws;
  size_t off = 0;
  auto take = [&](size_t bytes) {
    char* p = ws + off; off += (bytes + 255) & ~(size_t)255; return p;
  };
  unsigned short* xb   = (unsigned short*)take((size_t)NTOK * DDIM * 2);        // 50.3 MB
  unsigned short* w1bt = (unsigned short*)take((size_t)NEXP * DDIM * HDIM * 2); // 37.7 MB
  unsigned short* w2bt = (unsigned short*)take((size_t)NEXP * DDIM * HDIM * 2); // 37.7 MB
  int*   tokidx = (int*)take((size_t)NEXP * CAP * 4);
  float* pw   = (float*)take((size_t)NTOK * 4);
  int*   slotof = (int*)take((size_t)NTOK * 2 * 4);
  int*   cnt  = (int*)take(256);
  unsigned short* Ybuf = (unsigned short*)take((size_t)NEXP * CAP * DDIM * 2);  // 125.8 MB

  size_t avail = (ws_size > off) ? (ws_size - off) : 0;
  long long cand = (long long)(avail / ((size_t)NEXP * HDIM * 2));  // rows/expert
  int Mc = (int)((cand / 256) * 256);
  if (Mc > CAP) Mc = CAP;
  if (Mc < 256) {
    sentinel_kernel<<<(NTOK * DDIM + 255) / 256, 256, 0, stream>>>(out, NTOK * DDIM);
    return;
  }
  unsigned short* Hbuf = (unsigned short*)take((size_t)NEXP * Mc * HDIM * 2);

  hipMemsetAsync(cnt, 0, NEXP * sizeof(int), stream);
  router_assign<<<NTOK / 32, 256, 0, stream>>>(x, wg, xb, pw, cnt, tokidx, slotof);
  transpose_all<<<576 * NEXP * 2, 256, 0, stream>>>(w1, w2, w1bt, w2bt);

  for (int mbase = 0; mbase < CAP; mbase += Mc) {
    int rows = CAP - mbase; if (rows > Mc) rows = Mc;
    int mt = rows / 256;
    {
      int L = NEXP * mt * (HDIM / 256);
      int g = L / 2; if (g > 256) g = 256; g &= ~7; if (g < 8) g = 8;
      moe_gemm<0, DDIM, HDIM><<<g, 512, 0, stream>>>(
          xb, w1bt, b1, cnt, tokidx, Hbuf, mbase, Mc, mt);
    }
    {
      int L = NEXP * mt * (DDIM / 256);
      int g = L / 2; if (g > 256) g = 256; g &= ~7; if (g < 8) g = 8;
      moe_gemm<1, HDIM, DDIM><<<g, 512, 0, stream>>>(
          Hbuf, w2bt, b2, cnt, tokidx, Ybuf, mbase, Mc, mt);
    }
  }

  combine_ln<<<NTOK / 8, 512, 0, stream>>>(Ybuf, slotof, pw, lnw, lnb, out);
}